// Round 9
// baseline (141.966 us; speedup 1.0000x reference)
//
#include <hip/hip_runtime.h>

typedef unsigned int u32;
typedef unsigned long long u64;

#define N_IMG 32
#define NA 67200
#define KTOP 1024
#define IM_F 1280.0f
#define HBLK 8           // private-histogram blocks per image
#define HBIN 4096        // 12-bit radix of u>>18 (u <= 0x3F7FFFFF -> bin <= 4063)
#define HCHUNK 8400      // NA / HBLK
#define BCAP 6144        // boundary-bin candidate cap (expected ~670)

// Correctly-rounded f32 exp via double (matches any faithful reference exp
// at virtually every point).
__device__ __forceinline__ float cr_expf(float x) { return (float)exp((double)x); }

__device__ __forceinline__ u64 readlane64(u64 v, int lane) {
    u32 lo = (u32)__builtin_amdgcn_readlane((int)(u32)v, lane);
    u32 hi = (u32)__builtin_amdgcn_readlane((int)(u32)(v >> 32), lane);
    return ((u64)hi << 32) | (u64)lo;
}

__device__ __forceinline__ u64 shflxor64(u64 v, int m) {
    u32 lo = (u32)__shfl_xor((int)(u32)v, m, 64);
    u32 hi = (u32)__shfl_xor((int)(u32)(v >> 32), m, 64);
    return ((u64)hi << 32) | (u64)lo;
}

// ---------------- K1: fused softmax score + private per-block histogram -------
__global__ __launch_bounds__(256) void score_hist_kernel(const float2* __restrict__ conf,
                                                         float* __restrict__ scores,
                                                         u32* __restrict__ hist) {
    const int n   = blockIdx.x >> 3;
    const int blk = blockIdx.x & 7;
    const int tid = threadIdx.x;
    __shared__ u32 h[HBIN];
    for (int i = tid; i < HBIN; i += 256) h[i] = 0;
    __syncthreads();
    const int base = n * NA + blk * HCHUNK;
    for (int a = base + tid; a < base + HCHUNK; a += 256) {
        float2 c = conf[a];
        float m  = fmaxf(c.x, c.y);
        float e0 = cr_expf(c.x - m);   // one of these is exp(0)=1 exactly
        float e1 = cr_expf(c.y - m);
        float s  = e1 / (e0 + e1);
        scores[a] = s;
        atomicAdd(&h[__float_as_uint(s) >> 18], 1u);
    }
    __syncthreads();
    u32* out = hist + ((size_t)n * HBLK + blk) * HBIN;
    for (int i = tid; i < HBIN; i += 256) out[i] = h[i];
}

// ---------------- K2: fused thresh + exact select + register bitonic + decode --
// key = (score_bits<<32)|~idx ; desc key == score desc, index asc (lax.top_k ties).
// Sort: element-per-thread register bitonic; strides <=32 via shfl_xor (no
// barriers), strides >=64 via LDS exchange (10 stages, 20 barriers total).
__global__ __launch_bounds__(1024) void select_kernel(const float* __restrict__ scores,
                                                      const u32* __restrict__ hist,
                                                      const float* __restrict__ loc,
                                                      const float* __restrict__ landms,
                                                      const float* __restrict__ priors,
                                                      float* __restrict__ top_score,
                                                      float* __restrict__ det) {
    const int n = blockIdx.x, tid = threadIdx.x;
    const int lane = tid & 63;
    __shared__ u64 cand[KTOP];      // 8 KB
    __shared__ u64 bkeys[BCAP];     // 48 KB (aliased as sA/sB during prologue)
    __shared__ u32 cntd_s, cntb_s, res_b;
    u32* sA = (u32*)bkeys;
    u32* sB = sA + 1024;
    if (tid == 0) { cntd_s = 0; cntb_s = 0; }

    // --- prologue: crossing bin B (GE(B) >= KTOP > GT(B)) from histogram ---
    const u32* hb = hist + (size_t)n * HBLK * HBIN;
    u32 h0 = 0, h1 = 0, h2 = 0, h3 = 0;
    #pragma unroll
    for (int blk = 0; blk < HBLK; ++blk) {
        const uint4 p = *(const uint4*)(hb + blk * HBIN + tid * 4);
        h0 += p.x; h1 += p.y; h2 += p.z; h3 += p.w;
    }
    sA[tid] = h0 + h1 + h2 + h3;
    __syncthreads();
    u32 *src = sA, *dst = sB;
    for (int d = 1; d < 1024; d <<= 1) {
        dst[tid] = src[tid] + ((tid + d < 1024) ? src[tid + d] : 0u);
        __syncthreads();
        u32* t = src; src = dst; dst = t;
    }
    u32 GT3 = (tid + 1 < 1024) ? src[tid + 1] : 0u;   // sum over bins > 4*tid+3
    u32 GE3 = GT3 + h3;
    u32 GE2 = GE3 + h2;
    u32 GE1 = GE2 + h1;
    u32 GE0 = GE1 + h0;
    if (GE3 >= KTOP && GT3 < KTOP) res_b = 4u * tid + 3u;
    if (GE2 >= KTOP && GE3 < KTOP) res_b = 4u * tid + 2u;
    if (GE1 >= KTOP && GE2 < KTOP) res_b = 4u * tid + 1u;
    if (GE0 >= KTOP && GE1 < KTOP) res_b = 4u * tid + 0u;
    __syncthreads();                 // sA/sB dead after this; bkeys reusable
    const u32 B = res_b;

    // --- scan + compact (float4 loads, wave-aggregated LDS allocation) ---
    const float4* s4 = (const float4*)(scores + (size_t)n * NA);   // NA%4==0
    #pragma unroll 1
    for (int i0 = 0; i0 < 20; i0 += 4) {
        float4 f[4];
        #pragma unroll
        for (int b = 0; b < 4; ++b) {
            int idx = tid + (i0 + b) * 1024;
            f[b] = (idx < NA / 4) ? s4[idx] : make_float4(0.f, 0.f, 0.f, 0.f);
        }
        #pragma unroll
        for (int b = 0; b < 4; ++b) {
            int idx = tid + (i0 + b) * 1024;
            const float fe[4] = { f[b].x, f[b].y, f[b].z, f[b].w };
            #pragma unroll
            for (int e = 0; e < 4; ++e) {
                int a = idx * 4 + e;
                u32 u = __float_as_uint(fe[e]);
                u32 bin = u >> 18;
                bool valid = idx < NA / 4;
                bool isd = valid && (bin > B);
                bool isb = valid && (bin == B);
                u64 key = ((u64)u << 32) | (u32)(~(u32)a);
                u64 md = __ballot(isd);
                if (md) {
                    u32 first = (u32)__ffsll((long long)md) - 1u;
                    u32 base = 0;
                    if (lane == first) base = atomicAdd(&cntd_s, (u32)__popcll(md));
                    base = (u32)__shfl((int)base, (int)first);
                    if (isd) cand[base + __popcll(md & ((1ull << lane) - 1ull))] = key;
                }
                u64 mb = __ballot(isb);
                if (mb) {
                    u32 first = (u32)__ffsll((long long)mb) - 1u;
                    u32 base = 0;
                    if (lane == first) base = atomicAdd(&cntb_s, (u32)__popcll(mb));
                    base = (u32)__shfl((int)base, (int)first);
                    u32 p = base + __popcll(mb & ((1ull << lane) - 1ull));
                    if (isb && p < BCAP) bkeys[p] = key;
                }
            }
        }
    }
    __syncthreads();

    const int D = (int)cntd_s;               // == GT(B) < KTOP
    const int R = KTOP - D;                  // take R largest boundary keys
    const int E = min((int)cntb_s, BCAP);    // >= R by construction (GE(B) >= KTOP)
    for (int t = tid; t < E; t += 1024) {
        u64 k = bkeys[t];
        int rank = 0;
        for (int j = 0; j < E; ++j) rank += (bkeys[j] > k);   // keys unique (idx distinct)
        if (rank < R) cand[D + rank] = k;
    }
    __syncthreads();

    // --- register bitonic sort, descending, 1024 elements ---
    u64 v = cand[tid];
    #pragma unroll
    for (int kk = 1; kk <= 10; ++kk) {
        const int k = 1 << kk;
        #pragma unroll
        for (int jj = kk - 1; jj >= 0; --jj) {
            const int j = 1 << jj;
            u64 p;
            if (j >= 64) {
                cand[tid] = v;
                __syncthreads();
                p = cand[tid ^ j];
                __syncthreads();
            } else {
                p = shflxor64(v, j);
            }
            bool keep_max = (((tid & k) == 0) == ((tid & j) == 0));
            u64 mx = v > p ? v : p;
            u64 mn = v > p ? p : v;
            v = keep_max ? mx : mn;
        }
    }

    // --- fused decode + outputs (thread tid owns sorted rank tid) ---
    const u32 a = ~(u32)(v & 0xFFFFFFFFull);
    const float sc = __uint_as_float((u32)(v >> 32));
    top_score[n * KTOP + tid] = sc;

    float4 p = *(const float4*)(priors + (size_t)a * 4);
    float4 l = *(const float4*)(loc + ((size_t)n * NA + a) * 4);
    float cx = p.x + l.x * 0.1f * p.z;
    float cy = p.y + l.y * 0.1f * p.w;
    float w  = p.z * cr_expf(l.z * 0.2f);
    float h  = p.w * cr_expf(l.w * 0.2f);

    float* o = det + ((size_t)n * KTOP + tid) * 15;
    o[0] = (cx - w * 0.5f) * IM_F;
    o[1] = (cy - h * 0.5f) * IM_F;
    o[2] = (cx + w * 0.5f) * IM_F;
    o[3] = (cy + h * 0.5f) * IM_F;
    o[4] = sc;
    const float* mp = landms + ((size_t)n * NA + a) * 10;
    #pragma unroll
    for (int q = 0; q < 5; ++q) {
        o[5 + 2 * q]     = (p.x + mp[2 * q]     * 0.1f * p.z) * IM_F;
        o[5 + 2 * q + 1] = (p.y + mp[2 * q + 1] * 0.1f * p.w) * IM_F;
    }
}

// ---------------- K3: IoU suppression bitmask, wave-per-row + ballot ----------
__global__ __launch_bounds__(256) void mask_kernel(const float* __restrict__ det,
                                                   u64* __restrict__ mask) {
    const int n    = blockIdx.x >> 4;        // image
    const int sub  = blockIdx.x & 15;        // block within image
    const int wid  = threadIdx.x >> 6;       // wave in block
    const int lane = threadIdx.x & 63;
    const int q    = sub * 4 + wid;          // wave id within image, 0..63
    const int tid  = threadIdx.x;

    __shared__ float bx1[KTOP], by1[KTOP], bx2[KTOP], by2[KTOP], ba[KTOP];
    for (int j = tid; j < KTOP; j += 256) {
        const float* dr = det + ((size_t)n * KTOP + j) * 15;
        float x1 = dr[0], y1 = dr[1], x2 = dr[2], y2 = dr[3];
        bx1[j] = x1; by1[j] = y1; bx2[j] = x2; by2[j] = y2;
        ba[j] = fmaxf(x2 - x1, 0.f) * fmaxf(y2 - y1, 0.f);
    }
    __syncthreads();

    u64* mbase = mask + (size_t)n * KTOP * 16;
    #pragma unroll 1
    for (int k = 0; k < 16; ++k) {
        const int i = k * 64 + q;
        const float x1i = bx1[i], y1i = by1[i], x2i = bx2[i], y2i = by2[i], ai = ba[i];
        u64* orow = mbase + (size_t)i * 16;
        if (lane < k) orow[lane] = 0ull;               // zero low words
        #pragma unroll 1
        for (int w = k; w < 16; ++w) {
            const int j = w * 64 + lane;
            bool bit = false;
            if (j > i) {
                float xx1 = fmaxf(x1i, bx1[j]);
                float yy1 = fmaxf(y1i, by1[j]);
                float xx2 = fminf(x2i, bx2[j]);
                float yy2 = fminf(y2i, by2[j]);
                float inter = fmaxf(xx2 - xx1, 0.f) * fmaxf(yy2 - yy1, 0.f);
                float iou = inter / (ai + ba[j] - inter + 1e-9f);   // ref formula order
                bit = iou > 0.4f;
            }
            u64 m = __ballot(bit);
            if (lane == 0) orow[w] = m;
        }
    }
}

// ---------------- K4: group-structured greedy NMS + fused masked output -------
__global__ __launch_bounds__(1024) void nms_out_kernel(const float* __restrict__ top_score,
                                                       const u64* __restrict__ mask,
                                                       const float* __restrict__ det,
                                                       float* __restrict__ out) {
    const int n = blockIdx.x;
    const int tid = threadIdx.x;
    __shared__ u64 lmask[512 * 16];   // 64 KB: one half (512 rows x 16 words), swizzled

    const u64* mbase = mask + (size_t)n * KTOP * 16;
    u64 myw = 0;                      // lane w (0..15) holds keep word w
    if (tid < 64) {
        for (int g = 0; g < 16; ++g) {
            u64 b = __ballot(top_score[n * KTOP + g * 64 + tid] > 0.5f);
            if (tid == g) myw = b;
        }
    }

    const int lane = tid & 63;
    const int w16  = lane & 15;
    const int p4   = lane >> 4;       // 0..3 (for tid<64)

    #pragma unroll 1
    for (int half = 0; half < 2; ++half) {
        __syncthreads();   // protect lmask from previous half's readers
        #pragma unroll
        for (int k = 0; k < 8; ++k) {
            int idx = tid + k * 1024;          // linear u64 index within half
            int r = idx >> 4, w = idx & 15;
            lmask[(r << 4) | (w ^ (r & 15))] = mbase[(size_t)half * 8192 + idx];
        }
        __syncthreads();
        if (tid < 64) {
            #pragma unroll 1
            for (int gg = 0; gg < 8; ++gg) {
                const int g = half * 8 + gg;
                const int lbase = gg * 64;                   // local row base
                // (a) column preload
                const int rr = lbase + lane;
                u64 colw = lmask[(rr << 4) | (g ^ (rr & 15))];
                // (b) serial chain (SALU select chain; readlanes independent)
                u64 kw = readlane64(myw, g);
                #pragma unroll
                for (int l = 0; l < 64; ++l) {
                    u64 rl = readlane64(colw, l);
                    kw = ((kw >> l) & 1ull) ? (kw & ~rl) : kw;
                }
                // (c) branchless parallel suppression
                u64 acc = 0;
                #pragma unroll
                for (int k = 0; k < 16; ++k) {
                    const int r2 = lbase + p4 * 16 + k;
                    u64 row = lmask[(r2 << 4) | (w16 ^ (r2 & 15))];
                    u64 sel = (u64)0 - ((kw >> (p4 * 16 + k)) & 1ull);
                    acc |= row & sel;
                }
                acc |= shflxor64(acc, 16);
                acc |= shflxor64(acc, 32);   // lanes 0..15: full suppress word w16
                myw = (lane == g) ? kw : myw;
                myw &= ~acc;                 // idempotent for word g
            }
        }
    }
    __syncthreads();
    if (tid < 16) lmask[tid] = myw;   // publish keep bits (mask rows no longer needed)
    __syncthreads();

    // masked output write: 15360 floats per image, element-parallel (coalesced)
    const float* drow = det + (size_t)n * KTOP * 15;
    float* orow = out + (size_t)n * KTOP * 15;
    for (int e = tid; e < KTOP * 15; e += 1024) {
        int k = e / 15;
        float f = ((lmask[k >> 6] >> (k & 63)) & 1ull) ? 1.0f : 0.0f;
        orow[e] = drow[e] * f;
    }
}

extern "C" void kernel_launch(void* const* d_in, const int* in_sizes, int n_in,
                              void* d_out, int out_size, void* d_ws, size_t ws_size,
                              hipStream_t stream) {
    const float* loc    = (const float*)d_in[0];
    const float* conf   = (const float*)d_in[1];
    const float* landms = (const float*)d_in[2];
    const float* priors = (const float*)d_in[3];

    char* ws = (char*)d_ws;
    size_t off = 0;
    auto carve = [&](size_t bytes) { void* p = ws + off; off = (off + bytes + 255) & ~255ull; return p; };
    float* scores    = (float*)carve(sizeof(float) * (size_t)N_IMG * NA);
    float* top_score = (float*)carve(sizeof(float) * N_IMG * KTOP);
    float* det       = (float*)carve(sizeof(float) * N_IMG * KTOP * 15);
    u32*   hist      = (u32*)  carve(sizeof(u32)   * (size_t)N_IMG * HBLK * HBIN);  // 4 MB
    u64*   mask      = (u64*)  carve(sizeof(u64)   * (size_t)N_IMG * KTOP * 16);    // 4 MB

    score_hist_kernel<<<N_IMG * HBLK, 256, 0, stream>>>((const float2*)conf, scores, hist);
    select_kernel<<<N_IMG, 1024, 0, stream>>>(scores, hist, loc, landms, priors, top_score, det);
    mask_kernel<<<N_IMG * 16, 256, 0, stream>>>(det, mask);
    nms_out_kernel<<<N_IMG, 1024, 0, stream>>>(top_score, mask, det, (float*)d_out);
}

// Round 10
// 140.739 us; speedup vs baseline: 1.0087x; 1.0087x over previous
//
#include <hip/hip_runtime.h>

typedef unsigned int u32;
typedef unsigned long long u64;

#define N_IMG 32
#define NA 67200
#define KTOP 1024
#define IM_F 1280.0f
#define HBIN 4096        // 12-bit radix of u>>18 (u <= 0x3F800000 -> bin <= 4064)
#define NCHK 8           // compact blocks per image
#define CHUNK 8400       // NA / NCHK
#define BCAP 6144        // boundary cap per image (expected ~670)
#define BCAP_BLK 2048    // boundary cap per block (expected ~84)

// Correctly-rounded f32 exp via double (matches any faithful reference exp
// at virtually every point).
__device__ __forceinline__ float cr_expf(float x) { return (float)exp((double)x); }

__device__ __forceinline__ u64 shflxor64(u64 v, int m) {
    u32 lo = (u32)__shfl_xor((int)(u32)v, m, 64);
    u32 hi = (u32)__shfl_xor((int)(u32)(v >> 32), m, 64);
    return ((u64)hi << 32) | (u64)lo;
}

__device__ __forceinline__ u64 readlane64(u64 v, int lane) {
    u32 lo = (u32)__builtin_amdgcn_readlane((int)(u32)v, lane);
    u32 hi = (u32)__builtin_amdgcn_readlane((int)(u32)(v >> 32), lane);
    return ((u64)hi << 32) | (u64)lo;
}

// ---------------- K1: fused softmax score + per-image histogram ---------------
// LDS-private hist; flushed with global atomicAdd (4096 addresses/image,
// 8 adds/address total -- no contention).
__global__ __launch_bounds__(256) void score_hist_kernel(const float2* __restrict__ conf,
                                                         float* __restrict__ scores,
                                                         u32* __restrict__ hist) {
    const int n   = blockIdx.x >> 3;
    const int blk = blockIdx.x & 7;
    const int tid = threadIdx.x;
    __shared__ u32 h[HBIN];
    for (int i = tid; i < HBIN; i += 256) h[i] = 0;
    __syncthreads();
    const int base = n * NA + blk * CHUNK;
    for (int a = base + tid; a < base + CHUNK; a += 256) {
        float2 c = conf[a];
        float m  = fmaxf(c.x, c.y);
        float e0 = cr_expf(c.x - m);   // one of these is exp(0)=1 exactly
        float e1 = cr_expf(c.y - m);
        float s  = e1 / (e0 + e1);
        scores[a] = s;
        atomicAdd(&h[__float_as_uint(s) >> 18], 1u);
    }
    __syncthreads();
    u32* out = hist + (size_t)n * HBIN;
    for (int i = tid; i < HBIN; i += 256) {
        u32 v = h[i];
        if (v) atomicAdd(&out[i], v);
    }
}

// ---------------- K2: per-image crossing bin via LDS suffix scan -------------
// B such that GE(B) >= KTOP > GT(B).
__global__ __launch_bounds__(1024) void thresh_kernel(const u32* __restrict__ hist,
                                                      u32* __restrict__ thr) {
    const int n = blockIdx.x, tid = threadIdx.x;
    __shared__ u32 sA[1024], sB[1024];
    __shared__ u32 res_b;
    const uint4 p = *(const uint4*)(hist + (size_t)n * HBIN + tid * 4);
    u32 h0 = p.x, h1 = p.y, h2 = p.z, h3 = p.w;
    sA[tid] = h0 + h1 + h2 + h3;
    __syncthreads();
    u32 *src = sA, *dst = sB;
    for (int d = 1; d < 1024; d <<= 1) {
        dst[tid] = src[tid] + ((tid + d < 1024) ? src[tid + d] : 0u);
        __syncthreads();
        u32* t = src; src = dst; dst = t;
    }
    u32 GT3 = (tid + 1 < 1024) ? src[tid + 1] : 0u;   // sum over bins > 4*tid+3
    u32 GE3 = GT3 + h3;
    u32 GE2 = GE3 + h2;
    u32 GE1 = GE2 + h1;
    u32 GE0 = GE1 + h0;
    if (GE3 >= KTOP && GT3 < KTOP) res_b = 4u * tid + 3u;
    if (GE2 >= KTOP && GE3 < KTOP) res_b = 4u * tid + 2u;
    if (GE1 >= KTOP && GE2 < KTOP) res_b = 4u * tid + 1u;
    if (GE0 >= KTOP && GE1 < KTOP) res_b = 4u * tid + 0u;
    __syncthreads();
    if (tid == 0) thr[n] = res_b;
}

// ---------------- K3: full-chip compact (block-local lists, 2 atomics/block) --
// key = (score_bits<<32)|~idx ; desc key == score desc, index asc (lax.top_k ties).
__global__ __launch_bounds__(256) void compact_kernel(const float* __restrict__ scores,
                                                      const u32* __restrict__ thr,
                                                      u64* __restrict__ candd,
                                                      u64* __restrict__ candb,
                                                      u32* __restrict__ gcntd,
                                                      u32* __restrict__ gcntb) {
    const int n   = blockIdx.x >> 3;
    const int blk = blockIdx.x & 7;
    const int tid = threadIdx.x;
    __shared__ u64 dkeys[KTOP];          // definite hits in this chunk (<= D < 1024)
    __shared__ u64 bkeys_l[BCAP_BLK];
    __shared__ u32 cd, cb, based, baseb;
    if (tid == 0) { cd = 0; cb = 0; }
    __syncthreads();

    const u32 B = thr[n];
    const float4* s4 = (const float4*)(scores + (size_t)n * NA + blk * CHUNK);  // 2100 float4
    #pragma unroll 1
    for (int it = 0; it < 9; ++it) {
        const int idx = tid + it * 256;
        if (idx < CHUNK / 4) {
            float4 f = s4[idx];
            const float fe[4] = { f.x, f.y, f.z, f.w };
            #pragma unroll
            for (int e = 0; e < 4; ++e) {
                u32 u = __float_as_uint(fe[e]);
                u32 bin = u >> 18;
                if (bin >= B) {                        // rare (~1.6%)
                    u32 a = (u32)(blk * CHUNK + idx * 4 + e);   // within-image anchor
                    u64 key = ((u64)u << 32) | (u32)(~a);
                    if (bin > B) {
                        u32 p = atomicAdd(&cd, 1u);
                        dkeys[p] = key;
                    } else {
                        u32 p = atomicAdd(&cb, 1u);
                        if (p < BCAP_BLK) bkeys_l[p] = key;
                    }
                }
            }
        }
    }
    __syncthreads();
    const u32 cdl = cd, cbl = min(cb, (u32)BCAP_BLK);
    if (tid == 0) based = atomicAdd(&gcntd[n * 16], cdl);
    if (tid == 1) baseb = atomicAdd(&gcntb[n * 16], cbl);
    __syncthreads();
    for (u32 i = tid; i < cdl; i += 256) candd[(size_t)n * KTOP + based + i] = dkeys[i];
    for (u32 i = tid; i < cbl; i += 256) {
        u32 p = baseb + i;
        if (p < BCAP) candb[(size_t)n * BCAP + p] = bkeys_l[i];
    }
}

// ---------------- K4: exact select (rank-count) + register bitonic + decode ---
__global__ __launch_bounds__(1024) void select_final_kernel(const u64* __restrict__ candd,
                                                            const u64* __restrict__ candb,
                                                            const u32* __restrict__ gcntd,
                                                            const u32* __restrict__ gcntb,
                                                            const float* __restrict__ loc,
                                                            const float* __restrict__ landms,
                                                            const float* __restrict__ priors,
                                                            float* __restrict__ top_score,
                                                            float* __restrict__ det) {
    const int n = blockIdx.x, tid = threadIdx.x;
    __shared__ u64 cand[KTOP];      // 8 KB
    __shared__ u64 bk[BCAP];        // 48 KB

    const int D = (int)gcntd[n * 16];              // == GT(B) < KTOP
    const int R = KTOP - D;                        // take R largest boundary keys
    const int E = min((int)gcntb[n * 16], BCAP);   // >= R (GE(B) >= KTOP)
    if (tid < D) cand[tid] = candd[(size_t)n * KTOP + tid];
    for (int t = tid; t < E; t += 1024) bk[t] = candb[(size_t)n * BCAP + t];
    __syncthreads();
    for (int t = tid; t < E; t += 1024) {
        u64 k = bk[t];
        int rank = 0;
        for (int j = 0; j < E; ++j) rank += (bk[j] > k);   // keys unique (idx distinct)
        if (rank < R) cand[D + rank] = k;
    }
    __syncthreads();

    // register bitonic sort, descending, 1024 elements
    u64 v = cand[tid];
    #pragma unroll
    for (int kk = 1; kk <= 10; ++kk) {
        const int k = 1 << kk;
        #pragma unroll
        for (int jj = kk - 1; jj >= 0; --jj) {
            const int j = 1 << jj;
            u64 p;
            if (j >= 64) {
                cand[tid] = v;
                __syncthreads();
                p = cand[tid ^ j];
                __syncthreads();
            } else {
                p = shflxor64(v, j);
            }
            bool keep_max = (((tid & k) == 0) == ((tid & j) == 0));
            u64 mx = v > p ? v : p;
            u64 mn = v > p ? p : v;
            v = keep_max ? mx : mn;
        }
    }

    // fused decode + outputs (thread tid owns sorted rank tid)
    const u32 a = ~(u32)(v & 0xFFFFFFFFull);
    const float sc = __uint_as_float((u32)(v >> 32));
    top_score[n * KTOP + tid] = sc;

    float4 p = *(const float4*)(priors + (size_t)a * 4);
    float4 l = *(const float4*)(loc + ((size_t)n * NA + a) * 4);
    float cx = p.x + l.x * 0.1f * p.z;
    float cy = p.y + l.y * 0.1f * p.w;
    float w  = p.z * cr_expf(l.z * 0.2f);
    float h  = p.w * cr_expf(l.w * 0.2f);

    float* o = det + ((size_t)n * KTOP + tid) * 15;
    o[0] = (cx - w * 0.5f) * IM_F;
    o[1] = (cy - h * 0.5f) * IM_F;
    o[2] = (cx + w * 0.5f) * IM_F;
    o[3] = (cy + h * 0.5f) * IM_F;
    o[4] = sc;
    const float* mp = landms + ((size_t)n * NA + a) * 10;
    #pragma unroll
    for (int q = 0; q < 5; ++q) {
        o[5 + 2 * q]     = (p.x + mp[2 * q]     * 0.1f * p.z) * IM_F;
        o[5 + 2 * q + 1] = (p.y + mp[2 * q + 1] * 0.1f * p.w) * IM_F;
    }
}

// ---------------- K5: IoU suppression bitmask, wave-per-row + ballot ----------
__global__ __launch_bounds__(256) void mask_kernel(const float* __restrict__ det,
                                                   u64* __restrict__ mask) {
    const int n    = blockIdx.x >> 4;        // image
    const int sub  = blockIdx.x & 15;        // block within image
    const int wid  = threadIdx.x >> 6;       // wave in block
    const int lane = threadIdx.x & 63;
    const int q    = sub * 4 + wid;          // wave id within image, 0..63
    const int tid  = threadIdx.x;

    __shared__ float bx1[KTOP], by1[KTOP], bx2[KTOP], by2[KTOP], ba[KTOP];
    for (int j = tid; j < KTOP; j += 256) {
        const float* dr = det + ((size_t)n * KTOP + j) * 15;
        float x1 = dr[0], y1 = dr[1], x2 = dr[2], y2 = dr[3];
        bx1[j] = x1; by1[j] = y1; bx2[j] = x2; by2[j] = y2;
        ba[j] = fmaxf(x2 - x1, 0.f) * fmaxf(y2 - y1, 0.f);
    }
    __syncthreads();

    u64* mbase = mask + (size_t)n * KTOP * 16;
    #pragma unroll 1
    for (int k = 0; k < 16; ++k) {
        const int i = k * 64 + q;
        const float x1i = bx1[i], y1i = by1[i], x2i = bx2[i], y2i = by2[i], ai = ba[i];
        u64* orow = mbase + (size_t)i * 16;
        if (lane < k) orow[lane] = 0ull;               // zero low words
        #pragma unroll 1
        for (int w = k; w < 16; ++w) {
            const int j = w * 64 + lane;
            bool bit = false;
            if (j > i) {
                float xx1 = fmaxf(x1i, bx1[j]);
                float yy1 = fmaxf(y1i, by1[j]);
                float xx2 = fminf(x2i, bx2[j]);
                float yy2 = fminf(y2i, by2[j]);
                float inter = fmaxf(xx2 - xx1, 0.f) * fmaxf(yy2 - yy1, 0.f);
                float iou = inter / (ai + ba[j] - inter + 1e-9f);   // ref formula order
                bit = iou > 0.4f;
            }
            u64 m = __ballot(bit);
            if (lane == 0) orow[w] = m;
        }
    }
}

// ---------------- K6: group-structured greedy NMS + fused masked output -------
__global__ __launch_bounds__(1024) void nms_out_kernel(const float* __restrict__ top_score,
                                                       const u64* __restrict__ mask,
                                                       const float* __restrict__ det,
                                                       float* __restrict__ out) {
    const int n = blockIdx.x;
    const int tid = threadIdx.x;
    __shared__ u64 lmask[512 * 16];   // 64 KB: one half (512 rows x 16 words), swizzled

    const u64* mbase = mask + (size_t)n * KTOP * 16;
    u64 myw = 0;                      // lane w (0..15) holds keep word w
    if (tid < 64) {
        for (int g = 0; g < 16; ++g) {
            u64 b = __ballot(top_score[n * KTOP + g * 64 + tid] > 0.5f);
            if (tid == g) myw = b;
        }
    }

    const int lane = tid & 63;
    const int w16  = lane & 15;
    const int p4   = lane >> 4;       // 0..3 (for tid<64)

    #pragma unroll 1
    for (int half = 0; half < 2; ++half) {
        __syncthreads();   // protect lmask from previous half's readers
        #pragma unroll
        for (int k = 0; k < 8; ++k) {
            int idx = tid + k * 1024;          // linear u64 index within half
            int r = idx >> 4, w = idx & 15;
            lmask[(r << 4) | (w ^ (r & 15))] = mbase[(size_t)half * 8192 + idx];
        }
        __syncthreads();
        if (tid < 64) {
            #pragma unroll 1
            for (int gg = 0; gg < 8; ++gg) {
                const int g = half * 8 + gg;
                const int lbase = gg * 64;                   // local row base
                const int rr = lbase + lane;
                u64 colw = lmask[(rr << 4) | (g ^ (rr & 15))];
                u64 kw = readlane64(myw, g);
                #pragma unroll
                for (int l = 0; l < 64; ++l) {               // pure-register serial chain
                    u64 rl = readlane64(colw, l);
                    kw = ((kw >> l) & 1ull) ? (kw & ~rl) : kw;
                }
                u64 acc = 0;                                  // branchless suppression
                #pragma unroll
                for (int k = 0; k < 16; ++k) {
                    const int r2 = lbase + p4 * 16 + k;
                    u64 row = lmask[(r2 << 4) | (w16 ^ (r2 & 15))];
                    u64 sel = (u64)0 - ((kw >> (p4 * 16 + k)) & 1ull);
                    acc |= row & sel;
                }
                acc |= shflxor64(acc, 16);
                acc |= shflxor64(acc, 32);   // lanes 0..15: full suppress word w16
                myw = (lane == g) ? kw : myw;
                myw &= ~acc;                 // idempotent for word g
            }
        }
    }
    __syncthreads();
    if (tid < 16) lmask[tid] = myw;   // publish keep bits (mask rows no longer needed)
    __syncthreads();

    // masked output write: 15360 floats per image, element-parallel (coalesced)
    const float* drow = det + (size_t)n * KTOP * 15;
    float* orow = out + (size_t)n * KTOP * 15;
    for (int e = tid; e < KTOP * 15; e += 1024) {
        int k = e / 15;
        float f = ((lmask[k >> 6] >> (k & 63)) & 1ull) ? 1.0f : 0.0f;
        orow[e] = drow[e] * f;
    }
}

extern "C" void kernel_launch(void* const* d_in, const int* in_sizes, int n_in,
                              void* d_out, int out_size, void* d_ws, size_t ws_size,
                              hipStream_t stream) {
    const float* loc    = (const float*)d_in[0];
    const float* conf   = (const float*)d_in[1];
    const float* landms = (const float*)d_in[2];
    const float* priors = (const float*)d_in[3];

    char* ws = (char*)d_ws;
    size_t off = 0;
    auto carve = [&](size_t bytes) { void* p = ws + off; off = (off + bytes + 255) & ~255ull; return p; };
    float* scores    = (float*)carve(sizeof(float) * (size_t)N_IMG * NA);
    float* top_score = (float*)carve(sizeof(float) * N_IMG * KTOP);
    float* det       = (float*)carve(sizeof(float) * N_IMG * KTOP * 15);
    u32*   hist      = (u32*)  carve(sizeof(u32)   * (size_t)N_IMG * HBIN);        // 512 KB
    u64*   mask      = (u64*)  carve(sizeof(u64)   * (size_t)N_IMG * KTOP * 16);   // 4 MB
    u64*   candd     = (u64*)  carve(sizeof(u64)   * (size_t)N_IMG * KTOP);        // 256 KB
    u64*   candb     = (u64*)  carve(sizeof(u64)   * (size_t)N_IMG * BCAP);        // 1.5 MB
    u32*   gcnt      = (u32*)  carve(sizeof(u32)   * N_IMG * 16 * 2);              // 64B-padded counters
    u32*   thr       = (u32*)  carve(sizeof(u32)   * N_IMG);
    u32*   gcntd = gcnt, *gcntb = gcnt + N_IMG * 16;

    hipMemsetAsync(hist, 0, sizeof(u32) * (size_t)N_IMG * HBIN, stream);
    hipMemsetAsync(gcnt, 0, sizeof(u32) * N_IMG * 16 * 2, stream);

    score_hist_kernel<<<N_IMG * NCHK, 256, 0, stream>>>((const float2*)conf, scores, hist);
    thresh_kernel<<<N_IMG, 1024, 0, stream>>>(hist, thr);
    compact_kernel<<<N_IMG * NCHK, 256, 0, stream>>>(scores, thr, candd, candb, gcntd, gcntb);
    select_final_kernel<<<N_IMG, 1024, 0, stream>>>(candd, candb, gcntd, gcntb,
                                                    loc, landms, priors, top_score, det);
    mask_kernel<<<N_IMG * 16, 256, 0, stream>>>(det, mask);
    nms_out_kernel<<<N_IMG, 1024, 0, stream>>>(top_score, mask, det, (float*)d_out);
}

// Round 11
// 134.395 us; speedup vs baseline: 1.0563x; 1.0472x over previous
//
#include <hip/hip_runtime.h>

typedef unsigned int u32;
typedef unsigned long long u64;

#define N_IMG 32
#define NA 67200
#define KTOP 1024
#define IM_F 1280.0f
#define HBIN 4096        // 12-bit radix of u>>18 (u <= 0x3F800000 -> bin <= 4064)
#define HBLK 8           // private-histogram slabs per image
#define NCHK 8           // compact blocks per image
#define CHUNK 8400       // NA / NCHK
#define BCAP 6144        // boundary cap per image (expected ~670)
#define BCAP_BLK 2048    // boundary cap per block (expected ~84)

// Correctly-rounded f32 exp via double (matches any faithful reference exp
// at virtually every point).
__device__ __forceinline__ float cr_expf(float x) { return (float)exp((double)x); }

__device__ __forceinline__ u64 shflxor64(u64 v, int m) {
    u32 lo = (u32)__shfl_xor((int)(u32)v, m, 64);
    u32 hi = (u32)__shfl_xor((int)(u32)(v >> 32), m, 64);
    return ((u64)hi << 32) | (u64)lo;
}

__device__ __forceinline__ u64 readlane64(u64 v, int lane) {
    u32 lo = (u32)__builtin_amdgcn_readlane((int)(u32)v, lane);
    u32 hi = (u32)__builtin_amdgcn_readlane((int)(u32)(v >> 32), lane);
    return ((u64)hi << 32) | (u64)lo;
}

// ---------------- K1: fused softmax score + private per-slab histogram --------
// No global atomics, no pre-zeroing: each block owns a slab and writes every
// bin unconditionally (deterministic across graph replays).
__global__ __launch_bounds__(256) void score_hist_kernel(const float2* __restrict__ conf,
                                                         float* __restrict__ scores,
                                                         u32* __restrict__ hist) {
    const int n   = blockIdx.x >> 3;
    const int blk = blockIdx.x & 7;
    const int tid = threadIdx.x;
    __shared__ u32 h[HBIN];
    for (int i = tid; i < HBIN; i += 256) h[i] = 0;
    __syncthreads();
    const int base = n * NA + blk * CHUNK;
    for (int a = base + tid; a < base + CHUNK; a += 256) {
        float2 c = conf[a];
        float m  = fmaxf(c.x, c.y);
        float e0 = cr_expf(c.x - m);   // one of these is exp(0)=1 exactly
        float e1 = cr_expf(c.y - m);
        float s  = e1 / (e0 + e1);
        scores[a] = s;
        atomicAdd(&h[__float_as_uint(s) >> 18], 1u);
    }
    __syncthreads();
    u32* out = hist + ((size_t)n * HBLK + blk) * HBIN;
    for (int i = tid; i < HBIN; i += 256) out[i] = h[i];
}

// ---------------- K2: per-image crossing bin via LDS suffix scan -------------
// B such that GE(B) >= KTOP > GT(B). Also zeroes this image's global counters
// (replaces the pathological ~50us graph-captured hipMemsetAsync).
__global__ __launch_bounds__(1024) void thresh_kernel(const u32* __restrict__ hist,
                                                      u32* __restrict__ thr,
                                                      u32* __restrict__ gcntd,
                                                      u32* __restrict__ gcntb) {
    const int n = blockIdx.x, tid = threadIdx.x;
    __shared__ u32 sA[1024], sB[1024];
    __shared__ u32 res_b;
    if (tid == 0) { gcntd[n * 16] = 0; gcntb[n * 16] = 0; }
    const u32* hb = hist + (size_t)n * HBLK * HBIN;
    u32 h0 = 0, h1 = 0, h2 = 0, h3 = 0;
    #pragma unroll
    for (int blk = 0; blk < HBLK; ++blk) {
        const uint4 p = *(const uint4*)(hb + blk * HBIN + tid * 4);
        h0 += p.x; h1 += p.y; h2 += p.z; h3 += p.w;
    }
    sA[tid] = h0 + h1 + h2 + h3;
    __syncthreads();
    u32 *src = sA, *dst = sB;
    for (int d = 1; d < 1024; d <<= 1) {
        dst[tid] = src[tid] + ((tid + d < 1024) ? src[tid + d] : 0u);
        __syncthreads();
        u32* t = src; src = dst; dst = t;
    }
    u32 GT3 = (tid + 1 < 1024) ? src[tid + 1] : 0u;   // sum over bins > 4*tid+3
    u32 GE3 = GT3 + h3;
    u32 GE2 = GE3 + h2;
    u32 GE1 = GE2 + h1;
    u32 GE0 = GE1 + h0;
    if (GE3 >= KTOP && GT3 < KTOP) res_b = 4u * tid + 3u;
    if (GE2 >= KTOP && GE3 < KTOP) res_b = 4u * tid + 2u;
    if (GE1 >= KTOP && GE2 < KTOP) res_b = 4u * tid + 1u;
    if (GE0 >= KTOP && GE1 < KTOP) res_b = 4u * tid + 0u;
    __syncthreads();
    if (tid == 0) thr[n] = res_b;
}

// ---------------- K3: full-chip compact (block-local lists, 2 atomics/block) --
// key = (score_bits<<32)|~idx ; desc key == score desc, index asc (lax.top_k ties).
__global__ __launch_bounds__(256) void compact_kernel(const float* __restrict__ scores,
                                                      const u32* __restrict__ thr,
                                                      u64* __restrict__ candd,
                                                      u64* __restrict__ candb,
                                                      u32* __restrict__ gcntd,
                                                      u32* __restrict__ gcntb) {
    const int n   = blockIdx.x >> 3;
    const int blk = blockIdx.x & 7;
    const int tid = threadIdx.x;
    __shared__ u64 dkeys[KTOP];          // definite hits in this chunk (<= D < 1024)
    __shared__ u64 bkeys_l[BCAP_BLK];
    __shared__ u32 cd, cb, based, baseb;
    if (tid == 0) { cd = 0; cb = 0; }
    __syncthreads();

    const u32 B = thr[n];
    const float4* s4 = (const float4*)(scores + (size_t)n * NA + blk * CHUNK);  // 2100 float4
    #pragma unroll 1
    for (int it = 0; it < 9; ++it) {
        const int idx = tid + it * 256;
        if (idx < CHUNK / 4) {
            float4 f = s4[idx];
            const float fe[4] = { f.x, f.y, f.z, f.w };
            #pragma unroll
            for (int e = 0; e < 4; ++e) {
                u32 u = __float_as_uint(fe[e]);
                u32 bin = u >> 18;
                if (bin >= B) {                        // rare (~1.6%)
                    u32 a = (u32)(blk * CHUNK + idx * 4 + e);   // within-image anchor
                    u64 key = ((u64)u << 32) | (u32)(~a);
                    if (bin > B) {
                        u32 p = atomicAdd(&cd, 1u);
                        dkeys[p] = key;
                    } else {
                        u32 p = atomicAdd(&cb, 1u);
                        if (p < BCAP_BLK) bkeys_l[p] = key;
                    }
                }
            }
        }
    }
    __syncthreads();
    const u32 cdl = cd, cbl = min(cb, (u32)BCAP_BLK);
    if (tid == 0) based = atomicAdd(&gcntd[n * 16], cdl);
    if (tid == 1) baseb = atomicAdd(&gcntb[n * 16], cbl);
    __syncthreads();
    for (u32 i = tid; i < cdl; i += 256) candd[(size_t)n * KTOP + based + i] = dkeys[i];
    for (u32 i = tid; i < cbl; i += 256) {
        u32 p = baseb + i;
        if (p < BCAP) candb[(size_t)n * BCAP + p] = bkeys_l[i];
    }
}

// ---------------- K4: exact select (rank-count) + register bitonic + decode ---
__global__ __launch_bounds__(1024) void select_final_kernel(const u64* __restrict__ candd,
                                                            const u64* __restrict__ candb,
                                                            const u32* __restrict__ gcntd,
                                                            const u32* __restrict__ gcntb,
                                                            const float* __restrict__ loc,
                                                            const float* __restrict__ landms,
                                                            const float* __restrict__ priors,
                                                            float* __restrict__ top_score,
                                                            float* __restrict__ det) {
    const int n = blockIdx.x, tid = threadIdx.x;
    __shared__ u64 cand[KTOP];      // 8 KB
    __shared__ u64 bk[BCAP];        // 48 KB

    const int D = (int)gcntd[n * 16];              // == GT(B) < KTOP
    const int R = KTOP - D;                        // take R largest boundary keys
    const int E = min((int)gcntb[n * 16], BCAP);   // >= R (GE(B) >= KTOP)
    if (tid < D) cand[tid] = candd[(size_t)n * KTOP + tid];
    for (int t = tid; t < E; t += 1024) bk[t] = candb[(size_t)n * BCAP + t];
    __syncthreads();
    for (int t = tid; t < E; t += 1024) {
        u64 k = bk[t];
        int rank = 0;
        for (int j = 0; j < E; ++j) rank += (bk[j] > k);   // keys unique (idx distinct)
        if (rank < R) cand[D + rank] = k;
    }
    __syncthreads();

    // register bitonic sort, descending, 1024 elements
    u64 v = cand[tid];
    #pragma unroll
    for (int kk = 1; kk <= 10; ++kk) {
        const int k = 1 << kk;
        #pragma unroll
        for (int jj = kk - 1; jj >= 0; --jj) {
            const int j = 1 << jj;
            u64 p;
            if (j >= 64) {
                cand[tid] = v;
                __syncthreads();
                p = cand[tid ^ j];
                __syncthreads();
            } else {
                p = shflxor64(v, j);
            }
            bool keep_max = (((tid & k) == 0) == ((tid & j) == 0));
            u64 mx = v > p ? v : p;
            u64 mn = v > p ? p : v;
            v = keep_max ? mx : mn;
        }
    }

    // fused decode + outputs (thread tid owns sorted rank tid)
    const u32 a = ~(u32)(v & 0xFFFFFFFFull);
    const float sc = __uint_as_float((u32)(v >> 32));
    top_score[n * KTOP + tid] = sc;

    float4 p = *(const float4*)(priors + (size_t)a * 4);
    float4 l = *(const float4*)(loc + ((size_t)n * NA + a) * 4);
    float cx = p.x + l.x * 0.1f * p.z;
    float cy = p.y + l.y * 0.1f * p.w;
    float w  = p.z * cr_expf(l.z * 0.2f);
    float h  = p.w * cr_expf(l.w * 0.2f);

    float* o = det + ((size_t)n * KTOP + tid) * 15;
    o[0] = (cx - w * 0.5f) * IM_F;
    o[1] = (cy - h * 0.5f) * IM_F;
    o[2] = (cx + w * 0.5f) * IM_F;
    o[3] = (cy + h * 0.5f) * IM_F;
    o[4] = sc;
    const float* mp = landms + ((size_t)n * NA + a) * 10;
    #pragma unroll
    for (int q = 0; q < 5; ++q) {
        o[5 + 2 * q]     = (p.x + mp[2 * q]     * 0.1f * p.z) * IM_F;
        o[5 + 2 * q + 1] = (p.y + mp[2 * q + 1] * 0.1f * p.w) * IM_F;
    }
}

// ---------------- K5: IoU suppression bitmask, wave-per-row + ballot ----------
__global__ __launch_bounds__(256) void mask_kernel(const float* __restrict__ det,
                                                   u64* __restrict__ mask) {
    const int n    = blockIdx.x >> 4;        // image
    const int sub  = blockIdx.x & 15;        // block within image
    const int wid  = threadIdx.x >> 6;       // wave in block
    const int lane = threadIdx.x & 63;
    const int q    = sub * 4 + wid;          // wave id within image, 0..63
    const int tid  = threadIdx.x;

    __shared__ float bx1[KTOP], by1[KTOP], bx2[KTOP], by2[KTOP], ba[KTOP];
    for (int j = tid; j < KTOP; j += 256) {
        const float* dr = det + ((size_t)n * KTOP + j) * 15;
        float x1 = dr[0], y1 = dr[1], x2 = dr[2], y2 = dr[3];
        bx1[j] = x1; by1[j] = y1; bx2[j] = x2; by2[j] = y2;
        ba[j] = fmaxf(x2 - x1, 0.f) * fmaxf(y2 - y1, 0.f);
    }
    __syncthreads();

    u64* mbase = mask + (size_t)n * KTOP * 16;
    #pragma unroll 1
    for (int k = 0; k < 16; ++k) {
        const int i = k * 64 + q;
        const float x1i = bx1[i], y1i = by1[i], x2i = bx2[i], y2i = by2[i], ai = ba[i];
        u64* orow = mbase + (size_t)i * 16;
        if (lane < k) orow[lane] = 0ull;               // zero low words
        #pragma unroll 1
        for (int w = k; w < 16; ++w) {
            const int j = w * 64 + lane;
            bool bit = false;
            if (j > i) {
                float xx1 = fmaxf(x1i, bx1[j]);
                float yy1 = fmaxf(y1i, by1[j]);
                float xx2 = fminf(x2i, bx2[j]);
                float yy2 = fminf(y2i, by2[j]);
                float inter = fmaxf(xx2 - xx1, 0.f) * fmaxf(yy2 - yy1, 0.f);
                float iou = inter / (ai + ba[j] - inter + 1e-9f);   // ref formula order
                bit = iou > 0.4f;
            }
            u64 m = __ballot(bit);
            if (lane == 0) orow[w] = m;
        }
    }
}

// ---------------- K6: group-structured greedy NMS + fused masked output -------
__global__ __launch_bounds__(1024) void nms_out_kernel(const float* __restrict__ top_score,
                                                       const u64* __restrict__ mask,
                                                       const float* __restrict__ det,
                                                       float* __restrict__ out) {
    const int n = blockIdx.x;
    const int tid = threadIdx.x;
    __shared__ u64 lmask[512 * 16];   // 64 KB: one half (512 rows x 16 words), swizzled

    const u64* mbase = mask + (size_t)n * KTOP * 16;
    u64 myw = 0;                      // lane w (0..15) holds keep word w
    if (tid < 64) {
        for (int g = 0; g < 16; ++g) {
            u64 b = __ballot(top_score[n * KTOP + g * 64 + tid] > 0.5f);
            if (tid == g) myw = b;
        }
    }

    const int lane = tid & 63;
    const int w16  = lane & 15;
    const int p4   = lane >> 4;       // 0..3 (for tid<64)

    #pragma unroll 1
    for (int half = 0; half < 2; ++half) {
        __syncthreads();   // protect lmask from previous half's readers
        #pragma unroll
        for (int k = 0; k < 8; ++k) {
            int idx = tid + k * 1024;          // linear u64 index within half
            int r = idx >> 4, w = idx & 15;
            lmask[(r << 4) | (w ^ (r & 15))] = mbase[(size_t)half * 8192 + idx];
        }
        __syncthreads();
        if (tid < 64) {
            #pragma unroll 1
            for (int gg = 0; gg < 8; ++gg) {
                const int g = half * 8 + gg;
                const int lbase = gg * 64;                   // local row base
                const int rr = lbase + lane;
                u64 colw = lmask[(rr << 4) | (g ^ (rr & 15))];
                u64 kw = readlane64(myw, g);
                #pragma unroll
                for (int l = 0; l < 64; ++l) {               // pure-register serial chain
                    u64 rl = readlane64(colw, l);
                    kw = ((kw >> l) & 1ull) ? (kw & ~rl) : kw;
                }
                u64 acc = 0;                                  // branchless suppression
                #pragma unroll
                for (int k = 0; k < 16; ++k) {
                    const int r2 = lbase + p4 * 16 + k;
                    u64 row = lmask[(r2 << 4) | (w16 ^ (r2 & 15))];
                    u64 sel = (u64)0 - ((kw >> (p4 * 16 + k)) & 1ull);
                    acc |= row & sel;
                }
                acc |= shflxor64(acc, 16);
                acc |= shflxor64(acc, 32);   // lanes 0..15: full suppress word w16
                myw = (lane == g) ? kw : myw;
                myw &= ~acc;                 // idempotent for word g
            }
        }
    }
    __syncthreads();
    if (tid < 16) lmask[tid] = myw;   // publish keep bits (mask rows no longer needed)
    __syncthreads();

    // masked output write: 15360 floats per image, element-parallel (coalesced)
    const float* drow = det + (size_t)n * KTOP * 15;
    float* orow = out + (size_t)n * KTOP * 15;
    for (int e = tid; e < KTOP * 15; e += 1024) {
        int k = e / 15;
        float f = ((lmask[k >> 6] >> (k & 63)) & 1ull) ? 1.0f : 0.0f;
        orow[e] = drow[e] * f;
    }
}

extern "C" void kernel_launch(void* const* d_in, const int* in_sizes, int n_in,
                              void* d_out, int out_size, void* d_ws, size_t ws_size,
                              hipStream_t stream) {
    const float* loc    = (const float*)d_in[0];
    const float* conf   = (const float*)d_in[1];
    const float* landms = (const float*)d_in[2];
    const float* priors = (const float*)d_in[3];

    char* ws = (char*)d_ws;
    size_t off = 0;
    auto carve = [&](size_t bytes) { void* p = ws + off; off = (off + bytes + 255) & ~255ull; return p; };
    float* scores    = (float*)carve(sizeof(float) * (size_t)N_IMG * NA);
    float* top_score = (float*)carve(sizeof(float) * N_IMG * KTOP);
    float* det       = (float*)carve(sizeof(float) * N_IMG * KTOP * 15);
    u32*   hist      = (u32*)  carve(sizeof(u32)   * (size_t)N_IMG * HBLK * HBIN); // 4 MB
    u64*   mask      = (u64*)  carve(sizeof(u64)   * (size_t)N_IMG * KTOP * 16);   // 4 MB
    u64*   candd     = (u64*)  carve(sizeof(u64)   * (size_t)N_IMG * KTOP);        // 256 KB
    u64*   candb     = (u64*)  carve(sizeof(u64)   * (size_t)N_IMG * BCAP);        // 1.5 MB
    u32*   gcnt      = (u32*)  carve(sizeof(u32)   * N_IMG * 16 * 2);              // 64B-padded counters
    u32*   thr       = (u32*)  carve(sizeof(u32)   * N_IMG);
    u32*   gcntd = gcnt, *gcntb = gcnt + N_IMG * 16;

    score_hist_kernel<<<N_IMG * NCHK, 256, 0, stream>>>((const float2*)conf, scores, hist);
    thresh_kernel<<<N_IMG, 1024, 0, stream>>>(hist, thr, gcntd, gcntb);
    compact_kernel<<<N_IMG * NCHK, 256, 0, stream>>>(scores, thr, candd, candb, gcntd, gcntb);
    select_final_kernel<<<N_IMG, 1024, 0, stream>>>(candd, candb, gcntd, gcntb,
                                                    loc, landms, priors, top_score, det);
    mask_kernel<<<N_IMG * 16, 256, 0, stream>>>(det, mask);
    nms_out_kernel<<<N_IMG, 1024, 0, stream>>>(top_score, mask, det, (float*)d_out);
}